// Round 13
// baseline (558.577 us; speedup 1.0000x reference)
//
#include <hip/hip_runtime.h>
#include <hip/hip_bf16.h>

#define HIDDEN 256
#define IN_CH 128
#define SCH 4096   // edges per pass-1 block
#define EPT 16     // edges per thread

typedef __attribute__((ext_vector_type(8))) short bf16x8;
typedef __attribute__((ext_vector_type(4))) float f32x4;

__device__ inline float bf2f(unsigned short u) {
    union { unsigned int i; float f; } x; x.i = ((unsigned int)u) << 16; return x.f;
}
__device__ inline unsigned short f2bf(float f) {
    union { float f; unsigned int i; } x; x.f = f;
    unsigned int r = x.i + 0x7FFF + ((x.i >> 16) & 1);   // RNE
    return (unsigned short)(r >> 16);
}

// async global->LDS 16B copy (vmcnt-counted; compiler drains before s_barrier)
__device__ __forceinline__ void gload16(const void* g, void* l) {
    __builtin_amdgcn_global_load_lds(
        (__attribute__((address_space(1))) void*)const_cast<void*>(g),
        (__attribute__((address_space(3))) void*)(l), 16, 0, 0);
}

// ---------------- degree ----------------
__global__ void k_deg(const int* __restrict__ idx, int* __restrict__ deg, int E) {
    int e = blockIdx.x * blockDim.x + threadIdx.x;
    if (e < E) atomicAdd(&deg[idx[e]], 1);
}

// ---------------- chunk sums + dinv (merged) ----------------
__global__ void k_chunksum(const int* __restrict__ deg, int* __restrict__ part,
                           float* __restrict__ dinv, int N) {
    __shared__ int sh[256];
    int i = blockIdx.x * 256 + threadIdx.x;
    int v = (i < N) ? deg[i] : 0;
    if (i < N) dinv[i] = rsqrtf((float)v + 1.0f);
    sh[threadIdx.x] = v;
    __syncthreads();
    for (int st = 128; st > 0; st >>= 1) {
        if (threadIdx.x < st) sh[threadIdx.x] += sh[threadIdx.x + st];
        __syncthreads();
    }
    if (threadIdx.x == 0) part[blockIdx.x] = sh[0];
}

__global__ void k_scanpart(int* __restrict__ part, int nb) {
    __shared__ int sh[256];
    int v = (threadIdx.x < nb) ? part[threadIdx.x] : 0;
    sh[threadIdx.x] = v;
    __syncthreads();
    for (int st = 1; st < 256; st <<= 1) {
        int t = (threadIdx.x >= st) ? sh[threadIdx.x - st] : 0;
        __syncthreads();
        sh[threadIdx.x] += t;
        __syncthreads();
    }
    if (threadIdx.x < nb) part[threadIdx.x] = sh[threadIdx.x] - v;
}

// scanfinal + bucket bases (merged)
__global__ void k_scanfinal(const int* __restrict__ deg, const int* __restrict__ part,
                            int* __restrict__ offs, int* __restrict__ gcursor, int N, int E) {
    __shared__ int sh[256];
    int i = blockIdx.x * 256 + threadIdx.x;
    int v = (i < N) ? deg[i] : 0;
    sh[threadIdx.x] = v;
    __syncthreads();
    for (int st = 1; st < 256; st <<= 1) {
        int t = (threadIdx.x >= st) ? sh[threadIdx.x - st] : 0;
        __syncthreads();
        sh[threadIdx.x] += t;
        __syncthreads();
    }
    if (i < N) {
        int val = part[blockIdx.x] + sh[threadIdx.x] - v;
        offs[i] = val;
        if (threadIdx.x == 0) gcursor[blockIdx.x] = val;
    }
    if (i == 0) offs[N] = E;
}

// ---------------- binned sort pass 1 ----------------
__global__ __launch_bounds__(256) void k_binpass1(const int* __restrict__ src,
        const int* __restrict__ dst, int* __restrict__ gcursor,
        unsigned int* __restrict__ pairbuf, int E) {
    __shared__ int hist[256];
    __shared__ int base[256];
    int t = threadIdx.x;
    hist[t] = 0;
    __syncthreads();
    int e0 = blockIdx.x * SCH;
    int bkt[EPT], rnk[EPT];
    unsigned int pr[EPT];
#pragma unroll
    for (int j = 0; j < EPT; ++j) {
        int e = e0 + j * 256 + t;
        if (e < E) {
            int d = dst[e], s = src[e];
            int b = d >> 8;
            bkt[j] = b;
            rnk[j] = atomicAdd(&hist[b], 1);
            pr[j] = ((unsigned int)s << 8) | (unsigned int)(d & 255);
        } else bkt[j] = -1;
    }
    __syncthreads();
    base[t] = hist[t] ? atomicAdd(&gcursor[t], hist[t]) : 0;
    __syncthreads();
#pragma unroll
    for (int j = 0; j < EPT; ++j)
        if (bkt[j] >= 0)
            pairbuf[base[bkt[j]] + rnk[j]] = pr[j];
}

// ---------------- binned sort pass 2 ----------------
__global__ __launch_bounds__(256) void k_binpass2(const unsigned int* __restrict__ pairbuf,
        const int* __restrict__ offs, unsigned short* __restrict__ ssrc, int N) {
    __shared__ int lcur[256];
    int b = blockIdx.x;
    int t = threadIdx.x;
    int n0 = b * 256;
    int lim = N - n0; if (lim > 256) lim = 256;
    if (t < lim) lcur[t] = offs[n0 + t];
    __syncthreads();
    int beg = offs[n0];
    int end = offs[(n0 + 256 < N) ? (n0 + 256) : N];
    for (int i = beg + t; i < end; i += 256) {
        unsigned int p = pairbuf[i];
        int dl = p & 255;
        int pos = atomicAdd(&lcur[dl], 1);
        ssrc[pos] = (unsigned short)(p >> 8);
    }
}

// ---------------- merged prep: wfrag (blk<112), attn_pre (112..115), scale_xb (>=116) ----------------
__global__ __launch_bounds__(256) void k_prep(const float* __restrict__ x,
        const float* __restrict__ dinv, const float* __restrict__ W1,
        const float* __restrict__ W2, const float* __restrict__ ipw,
        const float* __restrict__ ipb, const float* __restrict__ opw,
        const float* __restrict__ opb,
        unsigned short* __restrict__ xb, unsigned short* __restrict__ wf1,
        unsigned short* __restrict__ wf2, unsigned short* __restrict__ wfq,
        unsigned short* __restrict__ wfk, float* __restrict__ wv_eff,
        float* __restrict__ vconst, float* __restrict__ bsum, int n4) {
    __shared__ float wsum_loc[64];
    __shared__ float red[256];
    int blk = blockIdx.x;
    int t = threadIdx.x;
    if (blk < 112) {
        int b = blk * 4 + (t >> 6);
        int l = t & 63;
        const float* src; unsigned short* wf; int sk, sn;
        if (b < 64)       { src = W1;          wf = wf1; sk = 256; sn = 1; }
        else if (b < 192) { src = W2;          wf = wf2; sk = 256; sn = 1; b -= 64; }
        else if (b < 320) { src = ipw;         wf = wfq; sk = 1;   sn = 256; b -= 192; }
        else              { src = ipw + 65536; wf = wfk; sk = 1;   sn = 256; b -= 320; }
        int ct = b & 15, kc32 = b >> 4;
        int k0 = kc32 * 32 + (l >> 4) * 8;
        int n = ct * 16 + (l & 15);
        unsigned short* o = wf + ((size_t)b * 64 + l) * 8;
#pragma unroll
        for (int j = 0; j < 8; ++j)
            o[j] = f2bf(src[(size_t)(k0 + j) * sk + (size_t)n * sn]);
    } else if (blk < 116) {
        int h = blk - 112;
        {
            int c = h * 64 + (t & 63);
            int j0 = (t >> 6) * 64;
            float s = 0.f;
            for (int j = j0; j < j0 + 64; ++j) s += opw[j * 256 + c];
            red[t] = s;
        }
        __syncthreads();
        if (t < 64) wsum_loc[t] = red[t] + red[t + 64] + red[t + 128] + red[t + 192];
        __syncthreads();
        {
            float s = 0.f;
            for (int c = 0; c < 64; ++c)
                s += wsum_loc[c] * ipw[(size_t)(512 + h * 64 + c) * 256 + t];
            wv_eff[h * 256 + t] = s;
        }
        if (t == 0) {
            float v = 0.f;
            for (int c = 0; c < 64; ++c) v += ipb[512 + h * 64 + c] * wsum_loc[c];
            vconst[h] = v;
        }
        if (h == 0) {
            __syncthreads();
            red[t] = opb[t];
            __syncthreads();
            for (int st = 128; st > 0; st >>= 1) {
                if (t < st) red[t] += red[t + st];
                __syncthreads();
            }
            if (t == 0) *bsum = red[0];
        }
    } else {
        int i = (blk - 116) * 256 + t;
        if (i < n4) {
            float4 v = reinterpret_cast<const float4*>(x)[i];
            float s = dinv[i >> 5];
            ushort4 u;
            u.x = f2bf(v.x * s); u.y = f2bf(v.y * s);
            u.z = f2bf(v.z * s); u.w = f2bf(v.w * s);
            reinterpret_cast<ushort4*>(xb)[i] = u;
        }
    }
}

// ---------------- fused layer1+layer2 GEMM: h (LDS only) then y2 ----------------
// y2 = dinv*( relu(aggx@W1 + a1*b1) @ W2 + b2 ), all bf16 in/out
__global__ __launch_bounds__(256) void k_mgemm12(const unsigned short* __restrict__ A,
        const unsigned short* __restrict__ wf1, const unsigned short* __restrict__ wf2,
        const float* __restrict__ b1, const float* __restrict__ a1v,
        const float* __restrict__ b2, const float* __restrict__ dinv,
        unsigned short* __restrict__ y2, int M) {
    __shared__ unsigned short Ws[2][8192];   // 32KB W double-buffer
    __shared__ unsigned short Ht[16384];     // 32KB h-tile [64][256], XOR-swizzled
    const int tid = threadIdx.x;
    const int lane = tid & 63;
    const int wid = tid >> 6;
    const int row0 = blockIdx.x * 64 + wid * 16;
    const bool active = row0 < M;

    f32x4 acc[16];
#pragma unroll
    for (int ct = 0; ct < 16; ++ct) acc[ct] = (f32x4){0.f, 0.f, 0.f, 0.f};

    int ar = row0 + (lane & 15); if (ar >= M) ar = M - 1;
    const unsigned short* arow = A + (size_t)ar * 128 + (lane >> 4) * 8;

    const int col0 = lane & 15;
    const int rsub = (lane >> 4) * 4;

    {   // stage wf1 chunk 0
#pragma unroll
        for (int j = 0; j < 4; ++j)
            gload16(wf1 + j * 2048 + tid * 8, &Ws[0][j * 2048 + tid * 8]);
    }
    __syncthreads();
    // ---- phase A: K=128, 4 chunks ----
#pragma unroll
    for (int c = 0; c < 4; ++c) {
        const unsigned short* nsrc = (c < 3) ? (wf1 + (size_t)(c + 1) * 8192) : wf2;
#pragma unroll
        for (int j = 0; j < 4; ++j)
            gload16(nsrc + j * 2048 + tid * 8, &Ws[(c + 1) & 1][j * 2048 + tid * 8]);
        bf16x8 a = *reinterpret_cast<const bf16x8*>(arow + c * 32);
        const bf16x8* wp = reinterpret_cast<const bf16x8*>(Ws[c & 1]) + lane;
#pragma unroll
        for (int ct = 0; ct < 16; ++ct)
            acc[ct] = __builtin_amdgcn_mfma_f32_16x16x32_bf16(a, wp[ct * 64], acc[ct], 0, 0, 0);
        __syncthreads();
    }
    // ---- epilogue 1: h -> Ht (swizzled), relu ----
    {
        float bsc[4];
#pragma unroll
        for (int r = 0; r < 4; ++r) {
            int gr = row0 + rsub + r; if (gr >= M) gr = M - 1;
            bsc[r] = a1v[gr];
        }
#pragma unroll
        for (int ct = 0; ct < 16; ++ct) {
            int col = ct * 16 + col0;
            float bv = b1[col];
#pragma unroll
            for (int r = 0; r < 4; ++r) {
                int lr = rsub + r;
                float v = fmaxf(acc[ct][r] + bsc[r] * bv, 0.f);
                int byte = (((wid * 16 + lr) * 512 + col * 2)) ^ ((lr & 7) << 4);
                Ht[byte >> 1] = f2bf(v);
            }
        }
#pragma unroll
        for (int ct = 0; ct < 16; ++ct) acc[ct] = (f32x4){0.f, 0.f, 0.f, 0.f};
    }
    __syncthreads();   // Ht visible + wf2 chunk0 drained
    // ---- phase B: K=256, 8 chunks; A from Ht ----
    const int lrB = lane & 15;
#pragma unroll
    for (int c = 0; c < 8; ++c) {
        if (c < 7) {
#pragma unroll
            for (int j = 0; j < 4; ++j)
                gload16(wf2 + (size_t)(c + 1) * 8192 + j * 2048 + tid * 8,
                        &Ws[(c + 1) & 1][j * 2048 + tid * 8]);
        }
        int byte = (((wid * 16 + lrB) * 512 + (c * 32 + (lane >> 4) * 8) * 2)) ^ ((lrB & 7) << 4);
        bf16x8 a = *reinterpret_cast<const bf16x8*>(&Ht[byte >> 1]);
        const bf16x8* wp = reinterpret_cast<const bf16x8*>(Ws[c & 1]) + lane;
#pragma unroll
        for (int ct = 0; ct < 16; ++ct)
            acc[ct] = __builtin_amdgcn_mfma_f32_16x16x32_bf16(a, wp[ct * 64], acc[ct], 0, 0, 0);
        __syncthreads();
    }
    if (!active) return;
    // ---- epilogue 2: y2 = dinv*(acc + b2) ----
    float rsc[4];
#pragma unroll
    for (int r = 0; r < 4; ++r) {
        int gr = row0 + rsub + r; if (gr >= M) gr = M - 1;
        rsc[r] = dinv[gr];
    }
#pragma unroll
    for (int ct = 0; ct < 16; ++ct) {
        int col = ct * 16 + col0;
        float bv = b2[col];
#pragma unroll
        for (int r = 0; r < 4; ++r) {
            int grow = row0 + rsub + r;
            if (grow < M)
                y2[(size_t)grow * 256 + col] = f2bf((acc[ct][r] + bv) * rsc[r]);
        }
    }
}

// ---------------- fused Q+K GEMM (sequential acc reuse) + qk_self ----------------
__global__ __launch_bounds__(256) void k_mgemm_qk2(const unsigned short* __restrict__ A,
        const unsigned short* __restrict__ wfq, const unsigned short* __restrict__ wfk,
        const float* __restrict__ ipb, unsigned short* __restrict__ Qb,
        unsigned short* __restrict__ Kb, float* __restrict__ qk_self, int M) {
    __shared__ unsigned short Ws[2][8192];
    const int tid = threadIdx.x;
    const int lane = tid & 63;
    const int row0 = blockIdx.x * 64 + (tid >> 6) * 16;
    const bool active = row0 < M;

    f32x4 acc[16];
#pragma unroll
    for (int ct = 0; ct < 16; ++ct) acc[ct] = (f32x4){0.f, 0.f, 0.f, 0.f};

    int ar = row0 + (lane & 15); if (ar >= M) ar = M - 1;
    const unsigned short* arow = A + (size_t)ar * 256 + (lane >> 4) * 8;

    const int col0 = lane & 15;
    const int rsub = (lane >> 4) * 4;
    bf16x8 av[8];

    {   // stage wfq chunk 0
#pragma unroll
        for (int j = 0; j < 4; ++j)
            gload16(wfq + j * 2048 + tid * 8, &Ws[0][j * 2048 + tid * 8]);
    }
    __syncthreads();
#pragma unroll
    for (int cc = 0; cc < 16; ++cc) {
        if (cc < 15) {
            const unsigned short* nsrc = (cc + 1 < 8) ? (wfq + (size_t)(cc + 1) * 8192)
                                                      : (wfk + (size_t)(cc + 1 - 8) * 8192);
#pragma unroll
            for (int j = 0; j < 4; ++j)
                gload16(nsrc + j * 2048 + tid * 8, &Ws[(cc + 1) & 1][j * 2048 + tid * 8]);
        }
        if (cc < 8) av[cc] = *reinterpret_cast<const bf16x8*>(arow + cc * 32);
        bf16x8 a = av[cc & 7];
        const bf16x8* wp = reinterpret_cast<const bf16x8*>(Ws[cc & 1]) + lane;
#pragma unroll
        for (int ct = 0; ct < 16; ++ct)
            acc[ct] = __builtin_amdgcn_mfma_f32_16x16x32_bf16(a, wp[ct * 64], acc[ct], 0, 0, 0);
        __syncthreads();
        if (cc == 7) {
            if (active) {   // Q epilogue
#pragma unroll
                for (int ct = 0; ct < 16; ++ct) {
                    int col = ct * 16 + col0;
                    float bq = ipb[col];
#pragma unroll
                    for (int r = 0; r < 4; ++r) {
                        int grow = row0 + rsub + r;
                        if (grow < M)
                            Qb[(size_t)grow * 256 + col] = f2bf(acc[ct][r] + bq);
                    }
                }
            }
#pragma unroll
            for (int ct = 0; ct < 16; ++ct) acc[ct] = (f32x4){0.f, 0.f, 0.f, 0.f};
        }
    }
    if (!active) return;
    // ---- K epilogue + qk_self ----
    float pq[4][4];
#pragma unroll
    for (int h = 0; h < 4; ++h)
#pragma unroll
        for (int r = 0; r < 4; ++r) pq[h][r] = 0.f;
#pragma unroll
    for (int ct = 0; ct < 16; ++ct) {
        int col = ct * 16 + col0;
        float bk = ipb[256 + col];
        int h = ct >> 2;
#pragma unroll
        for (int r = 0; r < 4; ++r) {
            int grow = row0 + rsub + r;
            if (grow < M) {
                float kv = acc[ct][r] + bk;
                Kb[(size_t)grow * 256 + col] = f2bf(kv);
                float qv = bf2f(Qb[(size_t)grow * 256 + col]);
                pq[h][r] = fmaf(qv, kv, pq[h][r]);
            }
        }
    }
#pragma unroll
    for (int h = 0; h < 4; ++h)
#pragma unroll
        for (int r = 0; r < 4; ++r) {
            pq[h][r] += __shfl_xor(pq[h][r], 1);
            pq[h][r] += __shfl_xor(pq[h][r], 2);
            pq[h][r] += __shfl_xor(pq[h][r], 4);
            pq[h][r] += __shfl_xor(pq[h][r], 8);
        }
    if (col0 == 0) {
#pragma unroll
        for (int r = 0; r < 4; ++r) {
            int grow = row0 + rsub + r;
            if (grow < M)
#pragma unroll
                for (int h = 0; h < 4; ++h) qk_self[grow * 4 + h] = pq[h][r];
        }
    }
}

// ---------------- gather, 128-dim bf16 rows + a1 ----------------
__global__ __launch_bounds__(256) void k_gather128b(const unsigned short* __restrict__ Xs,
        const int* __restrict__ offs, const unsigned short* __restrict__ ssrc,
        const float* __restrict__ dinv, unsigned short* __restrict__ outp,
        float* __restrict__ a1, int N) {
    int wid = threadIdx.x >> 6, lane = threadIdx.x & 63;
    int d = blockIdx.x * 4 + wid;
    if (d >= N) return;
    int beg = offs[d], end = offs[d + 1];
    ushort2 sv = reinterpret_cast<const ushort2*>(Xs + (size_t)d * 128)[lane];
    float a0 = bf2f(sv.x), av1 = bf2f(sv.y);
    float dsum = 0.f;
    int i = beg;
    for (; i + 8 <= end; i += 8) {
        int sIdx[8];
#pragma unroll
        for (int u = 0; u < 8; ++u) sIdx[u] = ssrc[i + u];
        ushort2 v[8];
#pragma unroll
        for (int u = 0; u < 8; ++u)
            v[u] = reinterpret_cast<const ushort2*>(Xs + (size_t)sIdx[u] * 128)[lane];
#pragma unroll
        for (int u = 0; u < 8; ++u) {
            a0 += bf2f(v[u].x); av1 += bf2f(v[u].y);
            dsum += dinv[sIdx[u]];
        }
    }
    for (; i < end; ++i) {
        int s = ssrc[i];
        ushort2 v = reinterpret_cast<const ushort2*>(Xs + (size_t)s * 128)[lane];
        a0 += bf2f(v.x); av1 += bf2f(v.y);
        dsum += dinv[s];
    }
    float sc = dinv[d];
    ushort2 r; r.x = f2bf(a0 * sc); r.y = f2bf(av1 * sc);
    reinterpret_cast<ushort2*>(outp + (size_t)d * 128)[lane] = r;
    if (lane == 0) a1[d] = sc * (dsum + sc);
}

// ---------------- gather, 256-dim bf16 rows + fused vw ----------------
__global__ __launch_bounds__(256) void k_gather256b_vw(const unsigned short* __restrict__ Ys,
        const int* __restrict__ offs, const unsigned short* __restrict__ ssrc,
        const float* __restrict__ dinv, const float* __restrict__ wv_eff,
        const float* __restrict__ vconst, unsigned short* __restrict__ outp,
        float* __restrict__ vw, int N) {
    int wid = threadIdx.x >> 6, lane = threadIdx.x & 63;
    int d = blockIdx.x * 4 + wid;
    if (d >= N) return;
    int beg = offs[d], end = offs[d + 1];
    ushort4 sv = reinterpret_cast<const ushort4*>(Ys + (size_t)d * 256)[lane];
    float a0 = bf2f(sv.x), a1 = bf2f(sv.y), a2 = bf2f(sv.z), a3 = bf2f(sv.w);
    int i = beg;
    for (; i + 8 <= end; i += 8) {
        ushort4 v[8];
#pragma unroll
        for (int u = 0; u < 8; ++u)
            v[u] = reinterpret_cast<const ushort4*>(Ys + (size_t)ssrc[i + u] * 256)[lane];
#pragma unroll
        for (int u = 0; u < 8; ++u) {
            a0 += bf2f(v[u].x); a1 += bf2f(v[u].y);
            a2 += bf2f(v[u].z); a3 += bf2f(v[u].w);
        }
    }
    for (; i < end; ++i) {
        ushort4 v = reinterpret_cast<const ushort4*>(Ys + (size_t)ssrc[i] * 256)[lane];
        a0 += bf2f(v.x); a1 += bf2f(v.y); a2 += bf2f(v.z); a3 += bf2f(v.w);
    }
    float sc = dinv[d];
    float z0 = a0 * sc, z1 = a1 * sc, z2 = a2 * sc, z3 = a3 * sc;
    ushort4 r;
    r.x = f2bf(z0); r.y = f2bf(z1); r.z = f2bf(z2); r.w = f2bf(z3);
    reinterpret_cast<ushort4*>(outp + (size_t)d * 256)[lane] = r;
    const float4* wv4 = reinterpret_cast<const float4*>(wv_eff);
    float ph0, ph1, ph2, ph3;
    {
        float4 w;
        w = wv4[0 * 64 + lane]; ph0 = z0 * w.x + z1 * w.y + z2 * w.z + z3 * w.w;
        w = wv4[1 * 64 + lane]; ph1 = z0 * w.x + z1 * w.y + z2 * w.z + z3 * w.w;
        w = wv4[2 * 64 + lane]; ph2 = z0 * w.x + z1 * w.y + z2 * w.z + z3 * w.w;
        w = wv4[3 * 64 + lane]; ph3 = z0 * w.x + z1 * w.y + z2 * w.z + z3 * w.w;
    }
    for (int st = 1; st < 64; st <<= 1) {
        ph0 += __shfl_xor(ph0, st);
        ph1 += __shfl_xor(ph1, st);
        ph2 += __shfl_xor(ph2, st);
        ph3 += __shfl_xor(ph3, st);
    }
    if (lane == 0) {
        vw[d * 4 + 0] = ph0 + vconst[0];
        vw[d * 4 + 1] = ph1 + vconst[1];
        vw[d * 4 + 2] = ph2 + vconst[2];
        vw[d * 4 + 3] = ph3 + vconst[3];
    }
}

// ---------------- per pred-edge final via MFMA: 1 wave = 16 edges ----------------
__global__ __launch_bounds__(256) void k_edge_pred_mfma(const unsigned short* __restrict__ Qb,
        const unsigned short* __restrict__ Kb, const float* __restrict__ qk_self,
        const float* __restrict__ vw, const float* __restrict__ bsum,
        const int* __restrict__ sp, const int* __restrict__ dp,
        float* __restrict__ out, int E) {
    int wid = threadIdx.x >> 6, lane = threadIdx.x & 63;
    int e0 = (blockIdx.x * 4 + wid) * 16;
    int i = lane & 15;
    int e = e0 + i; if (e >= E) e = E - 1;
    int s = sp[e], d = dp[e];
    const unsigned short* qrow = Qb + (size_t)s * 256 + (lane >> 4) * 8;
    const unsigned short* krow = Kb + (size_t)d * 256 + (lane >> 4) * 8;

    f32x4 acc[4];
#pragma unroll
    for (int h = 0; h < 4; ++h) acc[h] = (f32x4){0.f, 0.f, 0.f, 0.f};
#pragma unroll
    for (int h = 0; h < 4; ++h) {
#pragma unroll
        for (int c = 0; c < 2; ++c) {
            int kc = h * 64 + c * 32;
            bf16x8 a = *reinterpret_cast<const bf16x8*>(qrow + kc);
            bf16x8 b = *reinterpret_cast<const bf16x8*>(krow + kc);
            acc[h] = __builtin_amdgcn_mfma_f32_16x16x32_bf16(a, b, acc[h], 0, 0, 0);
        }
    }
    if (((lane & 15) >> 2) == (lane >> 4) && e0 + i < E) {
        int rr = lane & 3;
        const float scale = 0.125f;
        float4 qs  = *reinterpret_cast<const float4*>(qk_self + (size_t)s * 4);
        float4 vs4 = *reinterpret_cast<const float4*>(vw + (size_t)s * 4);
        float4 vd4 = *reinterpret_cast<const float4*>(vw + (size_t)d * 4);
        float csum = 0.f;
#pragma unroll
        for (int h = 0; h < 4; ++h) {
            float v0 = acc[h][0], v1 = acc[h][1], v2 = acc[h][2], v3 = acc[h][3];
            float lo = (rr & 1) ? v1 : v0;
            float hi = (rr & 1) ? v3 : v2;
            float dval = (rr & 2) ? hi : lo;
            float qsh = (h == 0) ? qs.x : (h == 1) ? qs.y : (h == 2) ? qs.z : qs.w;
            float vsh = (h == 0) ? vs4.x : (h == 1) ? vs4.y : (h == 2) ? vs4.z : vs4.w;
            float vdh = (h == 0) ? vd4.x : (h == 1) ? vd4.y : (h == 2) ? vd4.z : vd4.w;
            float delta = (dval - qsh) * scale;
            float sig = 1.f / (1.f + expf(-delta));
            csum += vsh + (vdh - vsh) * sig;
        }
        out[e] = 1.f / (1.f + expf(-(csum + *bsum)));
    }
}

extern "C" void kernel_launch(void* const* d_in, const int* in_sizes, int n_in,
                              void* d_out, int out_size, void* d_ws, size_t ws_size,
                              hipStream_t stream) {
    const float* x   = (const float*)d_in[0];
    const int*   ei  = (const int*)d_in[1];
    const int*   eip = (const int*)d_in[2];
    const float* W1  = (const float*)d_in[3];
    const float* b1  = (const float*)d_in[4];
    const float* W2  = (const float*)d_in[5];
    const float* b2  = (const float*)d_in[6];
    const float* ipw = (const float*)d_in[7];
    const float* ipb = (const float*)d_in[8];
    const float* opw = (const float*)d_in[9];
    const float* opb = (const float*)d_in[10];
    float* out = (float*)d_out;

    const int N = in_sizes[0] / IN_CH;      // 50000
    const int E = in_sizes[1] / 2;          // 1.6M
    const int EP = in_sizes[2] / 2;         // 500K

    float* wsf = (float*)d_ws;
    size_t o = 0;
    auto pad4 = [&](size_t v) { return (v + 3) & ~(size_t)3; };
    int*   deg     = (int*)(wsf + o); o += pad4(N);
    float* dinv    = wsf + o; o += pad4(N);
    float* a1v     = wsf + o; o += pad4(N);
    float* bsum    = wsf + o; o += 4;
    float* wv_eff  = wsf + o; o += 1024;
    float* vconst  = wsf + o; o += 4;
    unsigned short* wf1 = (unsigned short*)(wsf + o); o += 16384;
    unsigned short* wf2 = (unsigned short*)(wsf + o); o += 32768;
    unsigned short* wfq = (unsigned short*)(wsf + o); o += 32768;
    unsigned short* wfk = (unsigned short*)(wsf + o); o += 32768;
    float* qk_self = wsf + o; o += pad4((size_t)4 * N);
    float* vw      = wsf + o; o += pad4((size_t)4 * N);
    int*   offs    = (int*)(wsf + o); o += pad4((size_t)N + 1);
    int*   part    = (int*)(wsf + o); o += 256;
    int*   gcursor = (int*)(wsf + o); o += 256;
    unsigned int* pairbuf = (unsigned int*)(wsf + o); o += pad4(E);
    unsigned short* ssrc  = (unsigned short*)(wsf + o); o += pad4((size_t)(E + 1) / 2);
    float* B1      = wsf + o; o += (size_t)N * 128;   // xb -> y2
    float* B2      = wsf + o; o += (size_t)N * 128;   // aggx -> zb
    float* B3      = wsf + o; o += (size_t)N * 128;   // Kb
    float* B4      = wsf + o; o += (size_t)N * 128;   // Qb
    (void)ws_size; (void)n_in; (void)out_size;

    unsigned short* xb   = (unsigned short*)B1;
    unsigned short* y2   = (unsigned short*)B1;
    unsigned short* aggx = (unsigned short*)B2;
    unsigned short* zb   = (unsigned short*)B2;
    unsigned short* kb   = (unsigned short*)B3;
    unsigned short* qb   = (unsigned short*)B4;

    const int* src = ei;
    const int* dst = ei + E;
    const int* sp  = eip;
    const int* dp  = eip + EP;
    const int nb = (N + 255) / 256;      // scan blocks == bucket count
    const int aBlocks = (N + 3) / 4;
    const int gBlocks = (N + 63) / 64;
    const int n4 = N * 32;

    // ---- degree + offsets + bucket bases ----
    hipMemsetAsync(deg, 0, (size_t)pad4(N) * 4, stream);
    k_deg<<<(E + 255) / 256, 256, 0, stream>>>(dst, deg, E);
    k_chunksum<<<nb, 256, 0, stream>>>(deg, part, dinv, N);
    k_scanpart<<<1, 256, 0, stream>>>(part, nb);
    k_scanfinal<<<nb, 256, 0, stream>>>(deg, part, offs, gcursor, N, E);

    // ---- binned counting sort (2 passes) ----
    k_binpass1<<<(E + SCH - 1) / SCH, 256, 0, stream>>>(src, dst, gcursor, pairbuf, E);
    k_binpass2<<<nb, 256, 0, stream>>>(pairbuf, offs, ssrc, N);

    // ---- merged prep: wfrag + attn_pre + scale_xb (needs dinv) ----
    k_prep<<<116 + (n4 + 255) / 256, 256, 0, stream>>>(x, dinv, W1, W2, ipw, ipb, opw, opb,
                                                       xb, wf1, wf2, wfq, wfk,
                                                       wv_eff, vconst, bsum, n4);

    // ---- layer 1+2 fused: gather x, then h (LDS) -> y2 ----
    k_gather128b<<<aBlocks, 256, 0, stream>>>(xb, offs, ssrc, dinv, aggx, a1v, N);
    k_mgemm12<<<gBlocks, 256, 0, stream>>>(aggx, wf1, wf2, b1, a1v, b2, dinv, y2, N);

    // ---- z = gather(y2) (+vw fused) ----
    k_gather256b_vw<<<aBlocks, 256, 0, stream>>>(y2, offs, ssrc, dinv, wv_eff, vconst,
                                                 zb, vw, N);

    // ---- fused Q+K GEMM + qk_self ----
    k_mgemm_qk2<<<gBlocks, 256, 0, stream>>>(zb, wfq, wfk, ipb, qb, kb, qk_self, N);

    // ---- per pred edge via MFMA ----
    k_edge_pred_mfma<<<(EP + 63) / 64, 256, 0, stream>>>(qb, kb, qk_self, vw, bsum,
                                                         sp, dp, out, EP);
}

// Round 14
// 421.801 us; speedup vs baseline: 1.3243x; 1.3243x over previous
//
#include <hip/hip_runtime.h>
#include <hip/hip_bf16.h>

#define HIDDEN 256
#define IN_CH 128
#define SCH 4096   // edges per pass-1 block
#define EPT 16     // edges per thread

typedef __attribute__((ext_vector_type(8))) short bf16x8;
typedef __attribute__((ext_vector_type(4))) float f32x4;

__device__ inline float bf2f(unsigned short u) {
    union { unsigned int i; float f; } x; x.i = ((unsigned int)u) << 16; return x.f;
}
__device__ inline unsigned short f2bf(float f) {
    union { float f; unsigned int i; } x; x.f = f;
    unsigned int r = x.i + 0x7FFF + ((x.i >> 16) & 1);   // RNE
    return (unsigned short)(r >> 16);
}

// async global->LDS 16B copy (vmcnt-counted; compiler drains before s_barrier)
__device__ __forceinline__ void gload16(const void* g, void* l) {
    __builtin_amdgcn_global_load_lds(
        (__attribute__((address_space(1))) void*)const_cast<void*>(g),
        (__attribute__((address_space(3))) void*)(l), 16, 0, 0);
}

// ---------------- bucket histogram: bcnt[b] = #edges with dst>>8 == b ----------------
__global__ __launch_bounds__(256) void k_bhist(const int* __restrict__ dst,
                                               int* __restrict__ bcnt, int E) {
    __shared__ int h[256];
    int t = threadIdx.x;
    h[t] = 0;
    __syncthreads();
    int e0 = blockIdx.x * SCH;
#pragma unroll
    for (int j = 0; j < EPT; ++j) {
        int e = e0 + j * 256 + t;
        if (e < E) atomicAdd(&h[dst[e] >> 8], 1);
    }
    __syncthreads();
    if (h[t]) atomicAdd(&bcnt[t], h[t]);
}

// ---------------- bucket scan: bbase = exclusive scan(bcnt); gcursor = copy ----------------
__global__ void k_scanb(const int* __restrict__ bcnt, int* __restrict__ bbase,
                        int* __restrict__ gcursor, int E) {
    __shared__ int sh[256];
    int t = threadIdx.x;
    int v = bcnt[t];
    sh[t] = v;
    __syncthreads();
    for (int st = 1; st < 256; st <<= 1) {
        int u = (t >= st) ? sh[t - st] : 0;
        __syncthreads();
        sh[t] += u;
        __syncthreads();
    }
    int excl = sh[t] - v;
    bbase[t] = excl;
    gcursor[t] = excl;
    if (t == 0) bbase[256] = E;
}

// ---------------- binned sort pass 1 ----------------
__global__ __launch_bounds__(256) void k_binpass1(const int* __restrict__ src,
        const int* __restrict__ dst, int* __restrict__ gcursor,
        unsigned int* __restrict__ pairbuf, int E) {
    __shared__ int hist[256];
    __shared__ int base[256];
    int t = threadIdx.x;
    hist[t] = 0;
    __syncthreads();
    int e0 = blockIdx.x * SCH;
    int bkt[EPT], rnk[EPT];
    unsigned int pr[EPT];
#pragma unroll
    for (int j = 0; j < EPT; ++j) {
        int e = e0 + j * 256 + t;
        if (e < E) {
            int d = dst[e], s = src[e];
            int b = d >> 8;
            bkt[j] = b;
            rnk[j] = atomicAdd(&hist[b], 1);
            pr[j] = ((unsigned int)s << 8) | (unsigned int)(d & 255);
        } else bkt[j] = -1;
    }
    __syncthreads();
    base[t] = hist[t] ? atomicAdd(&gcursor[t], hist[t]) : 0;
    __syncthreads();
#pragma unroll
    for (int j = 0; j < EPT; ++j)
        if (bkt[j] >= 0)
            pairbuf[base[bkt[j]] + rnk[j]] = pr[j];
}

// ---------------- binned sort pass 2: also derives offs, dinv (deg-free) ----------------
__global__ __launch_bounds__(256) void k_binpass2(const unsigned int* __restrict__ pairbuf,
        const int* __restrict__ bbase, int* __restrict__ offs, float* __restrict__ dinv,
        unsigned short* __restrict__ ssrc, int N, int E) {
    __shared__ int cnt[256];
    __shared__ int loc[256];
    int b = blockIdx.x, t = threadIdx.x;
    int beg = bbase[b], end = bbase[b + 1];
    cnt[t] = 0;
    __syncthreads();
    for (int i = beg + t; i < end; i += 256)
        atomicAdd(&cnt[pairbuf[i] & 255], 1);
    __syncthreads();
    int myc = cnt[t];
    loc[t] = myc;
    __syncthreads();
    for (int st = 1; st < 256; st <<= 1) {
        int u = (t >= st) ? loc[t - st] : 0;
        __syncthreads();
        loc[t] += u;
        __syncthreads();
    }
    int excl = loc[t] - myc;
    int n0 = b * 256;
    if (n0 + t < N) {
        offs[n0 + t] = beg + excl;
        dinv[n0 + t] = rsqrtf((float)myc + 1.0f);
    }
    __syncthreads();
    loc[t] = beg + excl;   // reuse as placement cursor
    __syncthreads();
    for (int i = beg + t; i < end; i += 256) {
        unsigned int p = pairbuf[i];
        int pos = atomicAdd(&loc[p & 255], 1);
        ssrc[pos] = (unsigned short)(p >> 8);
    }
    if (b == gridDim.x - 1 && t == 0) offs[N] = E;
}

// ---------------- merged prep: wfrag (blk<112), attn_pre (112..115), scale_xb (>=116) ----------------
__global__ __launch_bounds__(256) void k_prep(const float* __restrict__ x,
        const float* __restrict__ dinv, const float* __restrict__ W1,
        const float* __restrict__ W2, const float* __restrict__ ipw,
        const float* __restrict__ ipb, const float* __restrict__ opw,
        const float* __restrict__ opb,
        unsigned short* __restrict__ xb, unsigned short* __restrict__ wf1,
        unsigned short* __restrict__ wf2, unsigned short* __restrict__ wfq,
        unsigned short* __restrict__ wfk, float* __restrict__ wv_eff,
        float* __restrict__ vconst, float* __restrict__ bsum, int n4) {
    __shared__ float wsum_loc[64];
    __shared__ float red[256];
    int blk = blockIdx.x;
    int t = threadIdx.x;
    if (blk < 112) {
        int b = blk * 4 + (t >> 6);
        int l = t & 63;
        const float* src; unsigned short* wf; int sk, sn;
        if (b < 64)       { src = W1;          wf = wf1; sk = 256; sn = 1; }
        else if (b < 192) { src = W2;          wf = wf2; sk = 256; sn = 1; b -= 64; }
        else if (b < 320) { src = ipw;         wf = wfq; sk = 1;   sn = 256; b -= 192; }
        else              { src = ipw + 65536; wf = wfk; sk = 1;   sn = 256; b -= 320; }
        int ct = b & 15, kc32 = b >> 4;
        int k0 = kc32 * 32 + (l >> 4) * 8;
        int n = ct * 16 + (l & 15);
        unsigned short* o = wf + ((size_t)b * 64 + l) * 8;
#pragma unroll
        for (int j = 0; j < 8; ++j)
            o[j] = f2bf(src[(size_t)(k0 + j) * sk + (size_t)n * sn]);
    } else if (blk < 116) {
        int h = blk - 112;
        {
            int c = h * 64 + (t & 63);
            int j0 = (t >> 6) * 64;
            float s = 0.f;
            for (int j = j0; j < j0 + 64; ++j) s += opw[j * 256 + c];
            red[t] = s;
        }
        __syncthreads();
        if (t < 64) wsum_loc[t] = red[t] + red[t + 64] + red[t + 128] + red[t + 192];
        __syncthreads();
        {
            float s = 0.f;
            for (int c = 0; c < 64; ++c)
                s += wsum_loc[c] * ipw[(size_t)(512 + h * 64 + c) * 256 + t];
            wv_eff[h * 256 + t] = s;
        }
        if (t == 0) {
            float v = 0.f;
            for (int c = 0; c < 64; ++c) v += ipb[512 + h * 64 + c] * wsum_loc[c];
            vconst[h] = v;
        }
        if (h == 0) {
            __syncthreads();
            red[t] = opb[t];
            __syncthreads();
            for (int st = 128; st > 0; st >>= 1) {
                if (t < st) red[t] += red[t + st];
                __syncthreads();
            }
            if (t == 0) *bsum = red[0];
        }
    } else {
        int i = (blk - 116) * 256 + t;
        if (i < n4) {
            float4 v = reinterpret_cast<const float4*>(x)[i];
            float s = dinv[i >> 5];
            ushort4 u;
            u.x = f2bf(v.x * s); u.y = f2bf(v.y * s);
            u.z = f2bf(v.z * s); u.w = f2bf(v.w * s);
            reinterpret_cast<ushort4*>(xb)[i] = u;
        }
    }
}

// ---------------- MFMA GEMM, async-staged double-buffered W ----------------
template<int K, int BF16OUT, int RELU>
__global__ __launch_bounds__(256) void k_mgemm(const unsigned short* __restrict__ A,
        const unsigned short* __restrict__ Wf, const float* __restrict__ bias,
        const float* __restrict__ rowscale, const float* __restrict__ bscale,
        void* __restrict__ Cout, int M) {
    __shared__ unsigned short Ws[2][8192];   // 2 x 16KB
    const int tid = threadIdx.x;
    const int lane = tid & 63;
    const int row0 = blockIdx.x * 64 + (tid >> 6) * 16;
    const bool active = row0 < M;

    f32x4 acc[16];
#pragma unroll
    for (int ct = 0; ct < 16; ++ct) acc[ct] = (f32x4){0.f, 0.f, 0.f, 0.f};

    int ar = row0 + (lane & 15); if (ar >= M) ar = M - 1;
    const unsigned short* arow = A + (size_t)ar * K + (lane >> 4) * 8;

    {   // async stage chunk 0
#pragma unroll
        for (int j = 0; j < 4; ++j)
            gload16(Wf + j * 2048 + tid * 8, &Ws[0][j * 2048 + tid * 8]);
    }
    __syncthreads();
    const int NC = K / 32;
#pragma unroll
    for (int c = 0; c < NC; ++c) {
        if (c + 1 < NC) {
#pragma unroll
            for (int j = 0; j < 4; ++j)
                gload16(Wf + (size_t)(c + 1) * 8192 + j * 2048 + tid * 8,
                        &Ws[(c + 1) & 1][j * 2048 + tid * 8]);
        }
        bf16x8 a = *reinterpret_cast<const bf16x8*>(arow + c * 32);
        const bf16x8* wp = reinterpret_cast<const bf16x8*>(Ws[c & 1]) + lane;
#pragma unroll
        for (int ct = 0; ct < 16; ++ct)
            acc[ct] = __builtin_amdgcn_mfma_f32_16x16x32_bf16(a, wp[ct * 64], acc[ct], 0, 0, 0);
        __syncthreads();
    }
    if (!active) return;

    const int col0 = lane & 15;
    const int rsub = (lane >> 4) * 4;
    float bsc[4], rsc[4];
#pragma unroll
    for (int r = 0; r < 4; ++r) {
        int grow = row0 + rsub + r;
        bsc[r] = bscale ? bscale[grow] : 1.f;
        rsc[r] = rowscale ? rowscale[grow] : 1.f;
    }
#pragma unroll
    for (int ct = 0; ct < 16; ++ct) {
        int col = ct * 16 + col0;
        float bv = bias[col];
#pragma unroll
        for (int r = 0; r < 4; ++r) {
            int grow = row0 + rsub + r;
            float v = (acc[ct][r] + bsc[r] * bv) * rsc[r];
            if (RELU) v = fmaxf(v, 0.f);
            if (BF16OUT) ((unsigned short*)Cout)[(size_t)grow * 256 + col] = f2bf(v);
            else          ((float*)Cout)[(size_t)grow * 256 + col] = v;
        }
    }
}

// ---------------- K-GEMM, async-staged, fused qk_self epilogue ----------------
__global__ __launch_bounds__(256) void k_mgemm_k_qk(const unsigned short* __restrict__ A,
        const unsigned short* __restrict__ Wf, const float* __restrict__ bias,
        const unsigned short* __restrict__ Qb, unsigned short* __restrict__ Kb,
        float* __restrict__ qk_self, int M) {
    __shared__ unsigned short Ws[2][8192];
    const int tid = threadIdx.x;
    const int lane = tid & 63;
    const int row0 = blockIdx.x * 64 + (tid >> 6) * 16;
    const bool active = row0 < M;

    f32x4 acc[16];
#pragma unroll
    for (int ct = 0; ct < 16; ++ct) acc[ct] = (f32x4){0.f, 0.f, 0.f, 0.f};

    int ar = row0 + (lane & 15); if (ar >= M) ar = M - 1;
    const unsigned short* arow = A + (size_t)ar * 256 + (lane >> 4) * 8;

    {
#pragma unroll
        for (int j = 0; j < 4; ++j)
            gload16(Wf + j * 2048 + tid * 8, &Ws[0][j * 2048 + tid * 8]);
    }
    __syncthreads();
#pragma unroll
    for (int c = 0; c < 8; ++c) {
        if (c + 1 < 8) {
#pragma unroll
            for (int j = 0; j < 4; ++j)
                gload16(Wf + (size_t)(c + 1) * 8192 + j * 2048 + tid * 8,
                        &Ws[(c + 1) & 1][j * 2048 + tid * 8]);
        }
        bf16x8 a = *reinterpret_cast<const bf16x8*>(arow + c * 32);
        const bf16x8* wp = reinterpret_cast<const bf16x8*>(Ws[c & 1]) + lane;
#pragma unroll
        for (int ct = 0; ct < 16; ++ct)
            acc[ct] = __builtin_amdgcn_mfma_f32_16x16x32_bf16(a, wp[ct * 64], acc[ct], 0, 0, 0);
        __syncthreads();
    }
    if (!active) return;

    const int col0 = lane & 15;
    const int rsub = (lane >> 4) * 4;
    float pq[4][4];
#pragma unroll
    for (int h = 0; h < 4; ++h)
#pragma unroll
        for (int r = 0; r < 4; ++r) pq[h][r] = 0.f;

#pragma unroll
    for (int ct = 0; ct < 16; ++ct) {
        int col = ct * 16 + col0;
        float bk = bias[col];
        int h = ct >> 2;
#pragma unroll
        for (int r = 0; r < 4; ++r) {
            int grow = row0 + rsub + r;
            float kv = acc[ct][r] + bk;
            Kb[(size_t)grow * 256 + col] = f2bf(kv);
            float qv = bf2f(Qb[(size_t)grow * 256 + col]);
            pq[h][r] = fmaf(qv, kv, pq[h][r]);
        }
    }
#pragma unroll
    for (int h = 0; h < 4; ++h)
#pragma unroll
        for (int r = 0; r < 4; ++r) {
            pq[h][r] += __shfl_xor(pq[h][r], 1);
            pq[h][r] += __shfl_xor(pq[h][r], 2);
            pq[h][r] += __shfl_xor(pq[h][r], 4);
            pq[h][r] += __shfl_xor(pq[h][r], 8);
        }
    if (col0 == 0) {
#pragma unroll
        for (int r = 0; r < 4; ++r) {
            int grow = row0 + rsub + r;
#pragma unroll
            for (int h = 0; h < 4; ++h) qk_self[grow * 4 + h] = pq[h][r];
        }
    }
}

// ---------------- gather, 128-dim bf16 rows + a1 ----------------
__global__ __launch_bounds__(256) void k_gather128b(const unsigned short* __restrict__ Xs,
        const int* __restrict__ offs, const unsigned short* __restrict__ ssrc,
        const float* __restrict__ dinv, unsigned short* __restrict__ outp,
        float* __restrict__ a1, int N) {
    int wid = threadIdx.x >> 6, lane = threadIdx.x & 63;
    int d = blockIdx.x * 4 + wid;
    if (d >= N) return;
    int beg = offs[d], end = offs[d + 1];
    ushort2 sv = reinterpret_cast<const ushort2*>(Xs + (size_t)d * 128)[lane];
    float a0 = bf2f(sv.x), av1 = bf2f(sv.y);
    float dsum = 0.f;
    int i = beg;
    for (; i + 8 <= end; i += 8) {
        int sIdx[8];
#pragma unroll
        for (int u = 0; u < 8; ++u) sIdx[u] = ssrc[i + u];
        ushort2 v[8];
#pragma unroll
        for (int u = 0; u < 8; ++u)
            v[u] = reinterpret_cast<const ushort2*>(Xs + (size_t)sIdx[u] * 128)[lane];
#pragma unroll
        for (int u = 0; u < 8; ++u) {
            a0 += bf2f(v[u].x); av1 += bf2f(v[u].y);
            dsum += dinv[sIdx[u]];
        }
    }
    for (; i < end; ++i) {
        int s = ssrc[i];
        ushort2 v = reinterpret_cast<const ushort2*>(Xs + (size_t)s * 128)[lane];
        a0 += bf2f(v.x); av1 += bf2f(v.y);
        dsum += dinv[s];
    }
    float sc = dinv[d];
    ushort2 r; r.x = f2bf(a0 * sc); r.y = f2bf(av1 * sc);
    reinterpret_cast<ushort2*>(outp + (size_t)d * 128)[lane] = r;
    if (lane == 0) a1[d] = sc * (dsum + sc);
}

// ---------------- gather, 256-dim bf16 rows + fused vw ----------------
__global__ __launch_bounds__(256) void k_gather256b_vw(const unsigned short* __restrict__ Ys,
        const int* __restrict__ offs, const unsigned short* __restrict__ ssrc,
        const float* __restrict__ dinv, const float* __restrict__ wv_eff,
        const float* __restrict__ vconst, unsigned short* __restrict__ outp,
        float* __restrict__ vw, int N) {
    int wid = threadIdx.x >> 6, lane = threadIdx.x & 63;
    int d = blockIdx.x * 4 + wid;
    if (d >= N) return;
    int beg = offs[d], end = offs[d + 1];
    ushort4 sv = reinterpret_cast<const ushort4*>(Ys + (size_t)d * 256)[lane];
    float a0 = bf2f(sv.x), a1 = bf2f(sv.y), a2 = bf2f(sv.z), a3 = bf2f(sv.w);
    int i = beg;
    for (; i + 8 <= end; i += 8) {
        ushort4 v[8];
#pragma unroll
        for (int u = 0; u < 8; ++u)
            v[u] = reinterpret_cast<const ushort4*>(Ys + (size_t)ssrc[i + u] * 256)[lane];
#pragma unroll
        for (int u = 0; u < 8; ++u) {
            a0 += bf2f(v[u].x); a1 += bf2f(v[u].y);
            a2 += bf2f(v[u].z); a3 += bf2f(v[u].w);
        }
    }
    for (; i < end; ++i) {
        ushort4 v = reinterpret_cast<const ushort4*>(Ys + (size_t)ssrc[i] * 256)[lane];
        a0 += bf2f(v.x); a1 += bf2f(v.y); a2 += bf2f(v.z); a3 += bf2f(v.w);
    }
    float sc = dinv[d];
    float z0 = a0 * sc, z1 = a1 * sc, z2 = a2 * sc, z3 = a3 * sc;
    ushort4 r;
    r.x = f2bf(z0); r.y = f2bf(z1); r.z = f2bf(z2); r.w = f2bf(z3);
    reinterpret_cast<ushort4*>(outp + (size_t)d * 256)[lane] = r;
    const float4* wv4 = reinterpret_cast<const float4*>(wv_eff);
    float ph0, ph1, ph2, ph3;
    {
        float4 w;
        w = wv4[0 * 64 + lane]; ph0 = z0 * w.x + z1 * w.y + z2 * w.z + z3 * w.w;
        w = wv4[1 * 64 + lane]; ph1 = z0 * w.x + z1 * w.y + z2 * w.z + z3 * w.w;
        w = wv4[2 * 64 + lane]; ph2 = z0 * w.x + z1 * w.y + z2 * w.z + z3 * w.w;
        w = wv4[3 * 64 + lane]; ph3 = z0 * w.x + z1 * w.y + z2 * w.z + z3 * w.w;
    }
    for (int st = 1; st < 64; st <<= 1) {
        ph0 += __shfl_xor(ph0, st);
        ph1 += __shfl_xor(ph1, st);
        ph2 += __shfl_xor(ph2, st);
        ph3 += __shfl_xor(ph3, st);
    }
    if (lane == 0) {
        vw[d * 4 + 0] = ph0 + vconst[0];
        vw[d * 4 + 1] = ph1 + vconst[1];
        vw[d * 4 + 2] = ph2 + vconst[2];
        vw[d * 4 + 3] = ph3 + vconst[3];
    }
}

// ---------------- per pred-edge final via MFMA: 1 wave = 16 edges ----------------
__global__ __launch_bounds__(256) void k_edge_pred_mfma(const unsigned short* __restrict__ Qb,
        const unsigned short* __restrict__ Kb, const float* __restrict__ qk_self,
        const float* __restrict__ vw, const float* __restrict__ bsum,
        const int* __restrict__ sp, const int* __restrict__ dp,
        float* __restrict__ out, int E) {
    int wid = threadIdx.x >> 6, lane = threadIdx.x & 63;
    int e0 = (blockIdx.x * 4 + wid) * 16;
    int i = lane & 15;
    int e = e0 + i; if (e >= E) e = E - 1;
    int s = sp[e], d = dp[e];
    const unsigned short* qrow = Qb + (size_t)s * 256 + (lane >> 4) * 8;
    const unsigned short* krow = Kb + (size_t)d * 256 + (lane >> 4) * 8;

    f32x4 acc[4];
#pragma unroll
    for (int h = 0; h < 4; ++h) acc[h] = (f32x4){0.f, 0.f, 0.f, 0.f};
#pragma unroll
    for (int h = 0; h < 4; ++h) {
#pragma unroll
        for (int c = 0; c < 2; ++c) {
            int kc = h * 64 + c * 32;
            bf16x8 a = *reinterpret_cast<const bf16x8*>(qrow + kc);
            bf16x8 b = *reinterpret_cast<const bf16x8*>(krow + kc);
            acc[h] = __builtin_amdgcn_mfma_f32_16x16x32_bf16(a, b, acc[h], 0, 0, 0);
        }
    }
    if (((lane & 15) >> 2) == (lane >> 4) && e0 + i < E) {
        int rr = lane & 3;
        const float scale = 0.125f;
        float4 qs  = *reinterpret_cast<const float4*>(qk_self + (size_t)s * 4);
        float4 vs4 = *reinterpret_cast<const float4*>(vw + (size_t)s * 4);
        float4 vd4 = *reinterpret_cast<const float4*>(vw + (size_t)d * 4);
        float csum = 0.f;
#pragma unroll
        for (int h = 0; h < 4; ++h) {
            float v0 = acc[h][0], v1 = acc[h][1], v2 = acc[h][2], v3 = acc[h][3];
            float lo = (rr & 1) ? v1 : v0;
            float hi = (rr & 1) ? v3 : v2;
            float dval = (rr & 2) ? hi : lo;
            float qsh = (h == 0) ? qs.x : (h == 1) ? qs.y : (h == 2) ? qs.z : qs.w;
            float vsh = (h == 0) ? vs4.x : (h == 1) ? vs4.y : (h == 2) ? vs4.z : vs4.w;
            float vdh = (h == 0) ? vd4.x : (h == 1) ? vd4.y : (h == 2) ? vd4.z : vd4.w;
            float delta = (dval - qsh) * scale;
            float sig = 1.f / (1.f + expf(-delta));
            csum += vsh + (vdh - vsh) * sig;
        }
        out[e] = 1.f / (1.f + expf(-(csum + *bsum)));
    }
}

extern "C" void kernel_launch(void* const* d_in, const int* in_sizes, int n_in,
                              void* d_out, int out_size, void* d_ws, size_t ws_size,
                              hipStream_t stream) {
    const float* x   = (const float*)d_in[0];
    const int*   ei  = (const int*)d_in[1];
    const int*   eip = (const int*)d_in[2];
    const float* W1  = (const float*)d_in[3];
    const float* b1  = (const float*)d_in[4];
    const float* W2  = (const float*)d_in[5];
    const float* b2  = (const float*)d_in[6];
    const float* ipw = (const float*)d_in[7];
    const float* ipb = (const float*)d_in[8];
    const float* opw = (const float*)d_in[9];
    const float* opb = (const float*)d_in[10];
    float* out = (float*)d_out;

    const int N = in_sizes[0] / IN_CH;      // 50000
    const int E = in_sizes[1] / 2;          // 1.6M
    const int EP = in_sizes[2] / 2;         // 500K

    float* wsf = (float*)d_ws;
    size_t o = 0;
    auto pad4 = [&](size_t v) { return (v + 3) & ~(size_t)3; };
    float* dinv    = wsf + o; o += pad4(N);
    float* a1v     = wsf + o; o += pad4(N);
    float* bsum    = wsf + o; o += 4;
    float* wv_eff  = wsf + o; o += 1024;
    float* vconst  = wsf + o; o += 4;
    unsigned short* wf1 = (unsigned short*)(wsf + o); o += 16384;
    unsigned short* wf2 = (unsigned short*)(wsf + o); o += 32768;
    unsigned short* wfq = (unsigned short*)(wsf + o); o += 32768;
    unsigned short* wfk = (unsigned short*)(wsf + o); o += 32768;
    float* qk_self = wsf + o; o += pad4((size_t)4 * N);
    float* vw      = wsf + o; o += pad4((size_t)4 * N);
    int*   offs    = (int*)(wsf + o); o += pad4((size_t)N + 1);
    int*   bcnt    = (int*)(wsf + o); o += 256;
    int*   bbase   = (int*)(wsf + o); o += 260;
    int*   gcursor = (int*)(wsf + o); o += 256;
    unsigned int* pairbuf = (unsigned int*)(wsf + o); o += pad4(E);
    unsigned short* ssrc  = (unsigned short*)(wsf + o); o += pad4((size_t)(E + 1) / 2);
    float* B1      = wsf + o; o += (size_t)N * 128;   // xb -> y2
    float* B2      = wsf + o; o += (size_t)N * 128;   // aggx -> zb
    float* B3      = wsf + o; o += (size_t)N * 128;   // Kb
    float* B4      = wsf + o; o += (size_t)N * 128;   // Qb
    (void)ws_size; (void)n_in; (void)out_size;

    unsigned short* xb   = (unsigned short*)B1;
    unsigned short* y2   = (unsigned short*)B1;
    unsigned short* aggx = (unsigned short*)B2;
    unsigned short* zb   = (unsigned short*)B2;
    unsigned short* kb   = (unsigned short*)B3;
    unsigned short* qb   = (unsigned short*)B4;

    const int* src = ei;
    const int* dst = ei + E;
    const int* sp  = eip;
    const int* dp  = eip + EP;
    const int nb = (N + 255) / 256;      // bucket count (196)
    const int aBlocks = (N + 3) / 4;
    const int gBlocks = (N + 63) / 64;
    const int n4 = N * 32;

    // ---- bucket histogram + scan + binned sort (also derives offs, dinv) ----
    hipMemsetAsync(bcnt, 0, 256 * 4, stream);
    k_bhist<<<(E + SCH - 1) / SCH, 256, 0, stream>>>(dst, bcnt, E);
    k_scanb<<<1, 256, 0, stream>>>(bcnt, bbase, gcursor, E);
    k_binpass1<<<(E + SCH - 1) / SCH, 256, 0, stream>>>(src, dst, gcursor, pairbuf, E);
    k_binpass2<<<nb, 256, 0, stream>>>(pairbuf, bbase, offs, dinv, ssrc, N, E);

    // ---- merged prep: wfrag + attn_pre + scale_xb (needs dinv) ----
    k_prep<<<116 + (n4 + 255) / 256, 256, 0, stream>>>(x, dinv, W1, W2, ipw, ipb, opw, opb,
                                                       xb, wf1, wf2, wfq, wfk,
                                                       wv_eff, vconst, bsum, n4);

    // ---- layer 1: aggregate x (commuted) + a1, then MFMA GEMM ----
    k_gather128b<<<aBlocks, 256, 0, stream>>>(xb, offs, ssrc, dinv, aggx, a1v, N);
    k_mgemm<128, 1, 1><<<gBlocks, 256, 0, stream>>>(aggx, wf1, b1, nullptr, a1v,
                                                    (unsigned short*)B3, N);  // hb in B3

    // ---- layer 2: y2 = dinv*(h@W2+b2) bf16; z = gather (+vw fused) ----
    k_mgemm<256, 1, 0><<<gBlocks, 256, 0, stream>>>((unsigned short*)B3, wf2, b2, dinv,
                                                    nullptr, y2, N);
    k_gather256b_vw<<<aBlocks, 256, 0, stream>>>(y2, offs, ssrc, dinv, wv_eff, vconst,
                                                 zb, vw, N);

    // ---- attention: Q GEMM, then fused K GEMM + qk_self ----
    k_mgemm<256, 1, 0><<<gBlocks, 256, 0, stream>>>(zb, wfq, ipb, nullptr, nullptr, qb, N);
    k_mgemm_k_qk<<<gBlocks, 256, 0, stream>>>(zb, wfk, ipb + 256, qb, kb, qk_self, N);

    // ---- per pred edge via MFMA ----
    k_edge_pred_mfma<<<(EP + 63) / 64, 256, 0, stream>>>(qb, kb, qk_self, vw, bsum,
                                                         sp, dp, out, EP);
}